// Round 6
// baseline (1443.919 us; speedup 1.0000x reference)
//
#include <hip/hip_runtime.h>

typedef unsigned short u16;
typedef unsigned int   u32;
typedef __attribute__((ext_vector_type(8))) short short8;
typedef __attribute__((ext_vector_type(4))) float f32x4;

struct __align__(8) u16x4 { u16 x, y, z, w; };

#define NL 7
#define M_DIM 131072              // B*S = 256*512

#define VMW(N) asm volatile("s_waitcnt vmcnt(" #N ")" ::: "memory")
#define LGW()  asm volatile("s_waitcnt lgkmcnt(0)" ::: "memory")
#define BAR()  __builtin_amdgcn_s_barrier()

__device__ __forceinline__ float b2f(u16 u) {
  union { float f; u32 i; } c; c.i = ((u32)u) << 16; return c.f;
}
__device__ __forceinline__ u16 f2b(float f) {
  union { float f; u32 i; } c; c.f = f;
  u32 r = c.i + 0x7FFFu + ((c.i >> 16) & 1u);
  return (u16)(r >> 16);
}
__device__ __forceinline__ void gload16(const void* g, void* l) {
  __builtin_amdgcn_global_load_lds((const __attribute__((address_space(1))) void*)g,
                                   (__attribute__((address_space(3))) void*)l, 16, 0, 0);
}
// XOR-swizzled [R][256] tile index: chunk = col>>3 (8-u16 / 16B units)
__device__ __forceinline__ int xIdx(int row, int chunk) {
  return row * 256 + (((chunk) ^ (row & 7)) << 3);
}

// ---------------- weight conversion (fp32 -> bf16, transposed to [N][K]) ----------------

__global__ __launch_bounds__(256) void conv_w1_k(const float* __restrict__ w1, u16* __restrict__ wT) {
  int idx = blockIdx.x * 256 + threadIdx.x;            // NL*256*256 ; [i][n][k]
  int i = idx >> 16, rem = idx & 65535;
  int n = rem >> 8, k = rem & 255;
  wT[idx] = f2b(w1[(i << 16) + (k << 8) + n]);
}

__global__ __launch_bounds__(256) void conv_wd_k(const float* __restrict__ wd, u16* __restrict__ wT) {
  int idx = blockIdx.x * 256 + threadIdx.x;            // NL*256*512 ; [i][n][k2], k2=tap*256+k
  int i = idx / 131072, rem = idx & 131071;
  int n = rem >> 9, k2 = rem & 511;
  int tap = k2 >> 8, k = k2 & 255;
  wT[idx] = f2b(wd[(((i * 2 + tap) << 8) + k) * 256 + n]);
}

__global__ __launch_bounds__(256) void conv_weg_k(const float* __restrict__ we, const float* __restrict__ wg,
                                                  u16* __restrict__ wT) {
  int idx = blockIdx.x * 256 + threadIdx.x;            // NL*2*256*256 ; [i][src][n][k]
  int i = idx / 131072, rem = idx & 131071;
  int src = rem >> 16, n = (rem >> 8) & 255, k = rem & 255;
  const float* W = src ? wg : we;
  wT[idx] = f2b(W[((i << 8) + k) * 256 + n]);
}

__global__ __launch_bounds__(256) void conv_wo_k(const float* __restrict__ outW, u16* __restrict__ wTo) {
  int idx = blockIdx.x * 256 + threadIdx.x;            // 32*256 ; [v][k]
  int v = idx >> 8, k = idx & 255;
  wTo[idx] = f2b(outW[k * 32 + v]);
}

// ---------------- zlat = z @ latent_W + latent_b  [256,256] fp32 ----------------

__global__ __launch_bounds__(256) void zlat_k(const float* __restrict__ z, const float* __restrict__ W,
                                              const float* __restrict__ bias, float* __restrict__ zlat) {
  int b = blockIdx.x, c = threadIdx.x;
  float acc = bias[c];
  for (int l = 0; l < 256; ++l) acc += z[b * 256 + l] * W[l * 256 + c];
  zlat[b * 256 + c] = acc;
}

// ---------------- embed: h = bf16(emb[x] + zlat) ----------------

__global__ __launch_bounds__(256) void embed_k(const int* __restrict__ x, const float* __restrict__ emb,
                                               const float* __restrict__ zlat, u16* __restrict__ h) {
  int wave = threadIdx.x >> 6, lane = threadIdx.x & 63;
  int r = blockIdx.x * 4 + wave;
  int c = lane * 4;
  int tok = x[r];
  int bi = r >> 9;
  float4 ev = *(const float4*)&emb[tok * 256 + c];
  float4 zv = *(const float4*)&zlat[bi * 256 + c];
  u16x4 hb;
  hb.x = f2b(ev.x + zv.x); hb.y = f2b(ev.y + zv.y);
  hb.z = f2b(ev.z + zv.z); hb.w = f2b(ev.w + zv.w);
  *(u16x4*)&h[(long)r * 256 + c] = hb;
}

// ---------------- gemm1: V = lrelu(LN2( lrelu(LN1(h)) @ w1 + b1 )) ----------------
// r6: + per-block K-rotation (ktL = (kt + rot) & 7) so concurrent blocks read
// DIFFERENT weight slices (breaks L2 hot-line convergence). 48KB -> 3 blocks/CU.

__global__ __launch_bounds__(256, 3) void gemm1_k(
    const u16* __restrict__ h, const u16* __restrict__ WT,
    const float* __restrict__ ln1g, const float* __restrict__ ln1b,
    const float* __restrict__ bias,
    const float* __restrict__ ln2g, const float* __restrict__ ln2b,
    u16* __restrict__ V)
{
  __shared__ __align__(16) u16 lA[64 * 256];     // 32768 B, LN1(h) tile, XOR-swizzled
  __shared__ __align__(16) u16 lB[256 * 32];     // 16384 B, per-kt B staging
  float* pS  = (float*)lB;
  float* pQ  = (float*)(lB + 512);
  float* muA = (float*)(lB + 1024);
  float* rsA = (float*)(lB + 1152);
  const int tid = threadIdx.x;
  const int lane = tid & 63;
  const int wv = tid >> 6;            // 0..3
  const int wc = wv * 64;
  const int m0 = blockIdx.x * 64;
  const int rA = tid >> 2;            // 0..63
  const int cSw = ((((tid & 3) - ((tid >> 3) & 3)) & 3)) * 8;
  const int lr = lane & 15;
  const int quad = lane >> 4;
  const int sw = ((quad + ((lr >> 1) & 3)) & 3) * 8;
  const int rg = (blockIdx.x >> 3) & 7;   // K-rotation (co-XCD blocks diverge)

  // ---- prologue: LN1 + lrelu of 16 rows per wave -> lA ----
  {
    const int half = lane >> 5, l5 = lane & 31;
    float4 ga = *(const float4*)&ln1g[l5 * 8];
    float4 gb = *(const float4*)&ln1g[l5 * 8 + 4];
    float4 ba = *(const float4*)&ln1b[l5 * 8];
    float4 bb = *(const float4*)&ln1b[l5 * 8 + 4];
    #pragma unroll 4
    for (int it = 0; it < 8; ++it) {
      int row = wv * 16 + it * 2 + half;
      uint4 hv = *(const uint4*)(h + (long)(m0 + row) * 256 + l5 * 8);
      float v0 = b2f((u16)(hv.x & 0xffff)), v1 = b2f((u16)(hv.x >> 16));
      float v2 = b2f((u16)(hv.y & 0xffff)), v3 = b2f((u16)(hv.y >> 16));
      float v4 = b2f((u16)(hv.z & 0xffff)), v5 = b2f((u16)(hv.z >> 16));
      float v6 = b2f((u16)(hv.w & 0xffff)), v7 = b2f((u16)(hv.w >> 16));
      float s = v0 + v1 + v2 + v3 + v4 + v5 + v6 + v7;
      float q = v0*v0 + v1*v1 + v2*v2 + v3*v3 + v4*v4 + v5*v5 + v6*v6 + v7*v7;
      #pragma unroll
      for (int o = 1; o < 32; o <<= 1) { s += __shfl_xor(s, o); q += __shfl_xor(q, o); }
      float mu = s * 0.00390625f;
      float var = q * 0.00390625f - mu * mu;
      float rs = rsqrtf(var + 1e-5f);
      float y0 = (v0 - mu) * rs * ga.x + ba.x; y0 = y0 >= 0.f ? y0 : 0.01f * y0;
      float y1 = (v1 - mu) * rs * ga.y + ba.y; y1 = y1 >= 0.f ? y1 : 0.01f * y1;
      float y2 = (v2 - mu) * rs * ga.z + ba.z; y2 = y2 >= 0.f ? y2 : 0.01f * y2;
      float y3 = (v3 - mu) * rs * ga.w + ba.w; y3 = y3 >= 0.f ? y3 : 0.01f * y3;
      float y4 = (v4 - mu) * rs * gb.x + bb.x; y4 = y4 >= 0.f ? y4 : 0.01f * y4;
      float y5 = (v5 - mu) * rs * gb.y + bb.y; y5 = y5 >= 0.f ? y5 : 0.01f * y5;
      float y6 = (v6 - mu) * rs * gb.z + bb.z; y6 = y6 >= 0.f ? y6 : 0.01f * y6;
      float y7 = (v7 - mu) * rs * gb.w + bb.w; y7 = y7 >= 0.f ? y7 : 0.01f * y7;
      uint4 ov;
      ov.x = (u32)f2b(y0) | ((u32)f2b(y1) << 16);
      ov.y = (u32)f2b(y2) | ((u32)f2b(y3) << 16);
      ov.z = (u32)f2b(y4) | ((u32)f2b(y5) << 16);
      ov.w = (u32)f2b(y6) | ((u32)f2b(y7) << 16);
      *(uint4*)&lA[xIdx(row, l5)] = ov;
    }
  }

  f32x4 acc[4][4];
  #pragma unroll
  for (int i = 0; i < 4; ++i)
    #pragma unroll
    for (int j = 0; j < 4; ++j) {
      acc[i][j][0] = 0.f; acc[i][j][1] = 0.f; acc[i][j][2] = 0.f; acc[i][j][3] = 0.f;
    }

  for (int kt = 0; kt < 8; ++kt) {
    const int ktL = (kt + rg) & 7;           // rotated K-slice
    const long bofs = (long)rA * 256 + ktL * 32 + cSw;
    #pragma unroll
    for (int j = 0; j < 4; ++j)
      gload16(WT + bofs + (long)(64 * j) * 256, &lB[tid * 8 + j * 2048]);
    __syncthreads();

    short8 af[4], bfr[4];
    #pragma unroll
    for (int mt = 0; mt < 4; ++mt)
      af[mt] = *(const short8*)&lA[xIdx(mt * 16 + lr, 4 * ktL + quad)];
    #pragma unroll
    for (int nt = 0; nt < 4; ++nt)
      bfr[nt] = *(const short8*)&lB[(wc + nt * 16 + lr) * 32 + sw];
    #pragma unroll
    for (int mt = 0; mt < 4; ++mt)
      #pragma unroll
      for (int nt = 0; nt < 4; ++nt)
        acc[mt][nt] = __builtin_amdgcn_mfma_f32_16x16x32_bf16(af[mt], bfr[nt], acc[mt][nt], 0, 0, 0);
    __syncthreads();
  }

  // ---- epilogue: bias + LN2 + lrelu -> V ----
  float biasv[4], gv[4], bv[4];
  #pragma unroll
  for (int nt = 0; nt < 4; ++nt) {
    int n = wc + nt * 16 + lr;
    biasv[nt] = bias[n]; gv[nt] = ln2g[n]; bv[nt] = ln2b[n];
  }
  #pragma unroll
  for (int mt = 0; mt < 4; ++mt)
    #pragma unroll
    for (int r = 0; r < 4; ++r) {
      float s = 0.f, q = 0.f;
      #pragma unroll
      for (int nt = 0; nt < 4; ++nt) {
        float v = acc[mt][nt][r] + biasv[nt];
        acc[mt][nt][r] = v;
        s += v; q += v * v;
      }
      #pragma unroll
      for (int o = 1; o < 16; o <<= 1) { s += __shfl_xor(s, o); q += __shfl_xor(q, o); }
      if (lr == 0) { pS[(mt * 16 + quad * 4 + r) * 4 + wv] = s; pQ[(mt * 16 + quad * 4 + r) * 4 + wv] = q; }
    }
  __syncthreads();
  if (tid < 64) {
    float S = pS[tid * 4 + 0] + pS[tid * 4 + 1] + pS[tid * 4 + 2] + pS[tid * 4 + 3];
    float Q = pQ[tid * 4 + 0] + pQ[tid * 4 + 1] + pQ[tid * 4 + 2] + pQ[tid * 4 + 3];
    float mu = S * 0.00390625f;
    float var = Q * 0.00390625f - mu * mu;
    muA[tid] = mu; rsA[tid] = rsqrtf(var + 1e-5f);
  }
  __syncthreads();
  #pragma unroll
  for (int mt = 0; mt < 4; ++mt)
    #pragma unroll
    for (int r = 0; r < 4; ++r) {
      int row = mt * 16 + quad * 4 + r;
      float mu = muA[row], rs = rsA[row];
      #pragma unroll
      for (int nt = 0; nt < 4; ++nt) {
        float y = (acc[mt][nt][r] - mu) * rs * gv[nt] + bv[nt];
        y = y >= 0.f ? y : 0.01f * y;
        V[(long)(m0 + row) * 256 + wc + nt * 16 + lr] = f2b(y);
      }
    }
}

// ---------------- FUSED conv+LN3+lrelu -> P(LDS) -> gate GEMMs -> h update ----------------
// r6 = r5 (M=128, 512 thr, dbuf + counted vmcnt) + per-block K-rotation in both
// phases: concurrent blocks read different weight slices each round, spreading
// the per-round weight hot-set across the full 128-512KB footprint (L2 banks).
// Tap0 zero-predicate and row-shift follow the LOGICAL kt.

__global__ __launch_bounds__(512, 2) void conv_gate_k(
    const u16* __restrict__ A,      // v  [M][256] bf16
    const u16* __restrict__ WTd,    // [256][512]  (n-major; k2 = tap*256+k)
    int dil,
    const float* __restrict__ bd3, const float* __restrict__ g3, const float* __restrict__ bb3,
    const u16* __restrict__ WTe, const u16* __restrict__ WTg,   // [256][256] each
    const float* __restrict__ bev_, const float* __restrict__ bgv_,
    u16* __restrict__ h)
{
  __shared__ __align__(16) u16 pT[128 * 256];    // 65536 B : P tile, XOR-swizzled
  __shared__ __align__(16) u16 stg[2][12288];    // 2 x 24576 B : A [0,4096) u16, B/W [4096,12288)
  // stats aliased into stg[0] A-region (dead after phase-1)
  float* pS  = (float*)stg[0];           // [128][4] bytes [0,2048)
  float* pQ  = (float*)(stg[0] + 1024);  //          bytes [2048,4096)
  float* muA = (float*)(stg[0] + 2048);  //          bytes [4096,4608)
  float* rsA = (float*)(stg[0] + 2304);  //          bytes [4608,5120)

  const int tid = threadIdx.x;
  const int lane = tid & 63;
  const int wv = tid >> 6;            // 0..7
  const int mw = wv >> 2;             // 0..1
  const int nw = wv & 3;              // 0..3
  const int rb = mw * 64;
  const int wc = nw * 64;
  const int m0 = blockIdx.x * 128;
  const int rA = tid >> 2;            // 0..127
  const int cSw = ((((tid & 3) - ((tid >> 3) & 3)) & 3)) * 8;
  const int lr = lane & 15;
  const int quad = lane >> 4;
  const int sw = ((quad + ((lr >> 1) & 3)) & 3) * 8;
  const int mm = m0 + rA;
  const int s1 = mm & 511;
  const int ro1 = (blockIdx.x >> 3) & 15;  // phase-1 rotation (16 rounds)
  const int ro2 = (blockIdx.x >> 3) & 7;   // phase-2 rotation (8 rounds)
  const short8 zero8 = {0, 0, 0, 0, 0, 0, 0, 0};

  // tap0 zero predicate per frag row
  bool zz[4];
  #pragma unroll
  for (int mt = 0; mt < 4; ++mt)
    zz[mt] = ((m0 + rb + mt * 16 + lr) & 511) < dil;

  // phase-1 staging, LOGICAL round KT (rotation applied inside)
#define STAGE1(KT, BB) do {                                                   \
    const int kt_ = ((KT) + ro1) & 15;                                        \
    const int kk_ = (kt_ & 7) * 32;                                           \
    const int rr_ = (kt_ < 8 && s1 >= dil) ? (mm - dil) : mm;                 \
    gload16(A + (long)rr_ * 256 + kk_ + cSw, &stg[BB][tid * 8]);              \
    const u16* bS_ = WTd + kt_ * 32 + cSw;                                    \
    gload16(bS_ + (long)rA * 512,         &stg[BB][4096 + tid * 8]);          \
    gload16(bS_ + (long)(rA + 128) * 512, &stg[BB][8192 + tid * 8]);          \
  } while (0)
  // phase-2 staging, LOGICAL round KT (rotation applied inside)
#define STAGEW(WP, KT, BB) do {                                               \
    const int kL_ = ((KT) + ro2) & 7;                                         \
    const long bofs_ = (long)rA * 256 + kL_ * 32 + cSw;                       \
    gload16((WP) + bofs_,              &stg[BB][4096 + tid * 8]);             \
    gload16((WP) + bofs_ + 128L * 256, &stg[BB][8192 + tid * 8]);             \
  } while (0)

  f32x4 acc[4][4];
  #pragma unroll
  for (int i = 0; i < 4; ++i)
    #pragma unroll
    for (int j = 0; j < 4; ++j) {
      acc[i][j][0] = 0.f; acc[i][j][1] = 0.f; acc[i][j][2] = 0.f; acc[i][j][3] = 0.f;
    }

  // ---- phase 1: conv GEMM over Ktot=512, rotated round order ----
  STAGE1(0, 0);
  STAGE1(1, 1);
  VMW(3);                              // buf0 ready (buf1's 3 in flight)
  BAR();

  #pragma unroll
  for (int r = 0; r < 16; ++r) {
    const int bb = r & 1;
    const int ktL = (r + ro1) & 15;    // logical K-slice sitting in buf bb
    short8 af[4], bfr[4];
    #pragma unroll
    for (int mt = 0; mt < 4; ++mt) {
      af[mt] = *(const short8*)&stg[bb][(rb + mt * 16 + lr) * 32 + sw];
      if (ktL < 8 && zz[mt]) af[mt] = zero8;
    }
    #pragma unroll
    for (int nt = 0; nt < 4; ++nt)
      bfr[nt] = *(const short8*)&stg[bb][4096 + (wc + nt * 16 + lr) * 32 + sw];
    LGW();                             // frags in regs
    BAR();                             // all waves done with buf bb -> safe to overwrite
    if (r <= 13)      STAGE1(r + 2, bb);
    else if (r == 14) STAGEW(WTe, 0, 0);     // prefetch E0 (buf0 W-region)
    else              STAGEW(WTe, 1, 1);     // r==15: E1
    #pragma unroll
    for (int mt = 0; mt < 4; ++mt)
      #pragma unroll
      for (int nt = 0; nt < 4; ++nt)
        acc[mt][nt] = __builtin_amdgcn_mfma_f32_16x16x32_bf16(af[mt], bfr[nt], acc[mt][nt], 0, 0, 0);
    if (r <= 13)      VMW(3);          // next buf ready
    else if (r == 14) VMW(2);          // stage(15) done; E0 in flight
    BAR();
  }

  // ---- epilogue 1: bias + LN3 stats + lrelu -> pT (stats in stg[0] A-region) ----
  float b3v[4], g3v[4], o3v[4];
  #pragma unroll
  for (int nt = 0; nt < 4; ++nt) {
    int n = wc + nt * 16 + lr;
    b3v[nt] = bd3[n]; g3v[nt] = g3[n]; o3v[nt] = bb3[n];
  }
  #pragma unroll
  for (int mt = 0; mt < 4; ++mt)
    #pragma unroll
    for (int r = 0; r < 4; ++r) {
      float s = 0.f, q = 0.f;
      #pragma unroll
      for (int nt = 0; nt < 4; ++nt) {
        float v = acc[mt][nt][r] + b3v[nt];
        acc[mt][nt][r] = v;
        s += v; q += v * v;
      }
      #pragma unroll
      for (int o = 1; o < 16; o <<= 1) { s += __shfl_xor(s, o); q += __shfl_xor(q, o); }
      if (lr == 0) {
        int row = rb + mt * 16 + quad * 4 + r;
        pS[row * 4 + nw] = s; pQ[row * 4 + nw] = q;
      }
    }
  LGW(); BAR();
  if (tid < 128) {
    float S = pS[tid * 4 + 0] + pS[tid * 4 + 1] + pS[tid * 4 + 2] + pS[tid * 4 + 3];
    float Q = pQ[tid * 4 + 0] + pQ[tid * 4 + 1] + pQ[tid * 4 + 2] + pQ[tid * 4 + 3];
    float mu = S * 0.00390625f;
    float var = Q * 0.00390625f - mu * mu;
    muA[tid] = mu; rsA[tid] = rsqrtf(var + 1e-5f);
  }
  LGW(); BAR();
  #pragma unroll
  for (int mt = 0; mt < 4; ++mt)
    #pragma unroll
    for (int r = 0; r < 4; ++r) {
      int row = rb + mt * 16 + quad * 4 + r;
      float mu = muA[row], rs = rsA[row];
      #pragma unroll
      for (int nt = 0; nt < 4; ++nt) {
        int col = wc + nt * 16 + lr;
        float y = (acc[mt][nt][r] - mu) * rs * g3v[nt] + o3v[nt];
        y = y >= 0.f ? y : 0.01f * y;
        pT[xIdx(row, col >> 3) + (col & 7)] = f2b(y);
      }
    }
  LGW(); VMW(2); BAR();                // pT visible; E0 staged (E1 in flight)

  // ---- phase 2a: accE = P @ we (K=256, dbuf, counted vmcnt, rotated) ----
  f32x4 accE[4][4], accG[4][4];
  #pragma unroll
  for (int i = 0; i < 4; ++i)
    #pragma unroll
    for (int j = 0; j < 4; ++j) {
      accE[i][j][0] = 0.f; accE[i][j][1] = 0.f; accE[i][j][2] = 0.f; accE[i][j][3] = 0.f;
      accG[i][j][0] = 0.f; accG[i][j][1] = 0.f; accG[i][j][2] = 0.f; accG[i][j][3] = 0.f;
    }

  #pragma unroll
  for (int k = 0; k < 8; ++k) {
    const int bb = k & 1;
    const int kL = (k + ro2) & 7;      // logical K-slice in buf bb
    short8 paf[4], bfe[4];
    #pragma unroll
    for (int mt = 0; mt < 4; ++mt)
      paf[mt] = *(const short8*)&pT[xIdx(rb + mt * 16 + lr, 4 * kL + quad)];
    #pragma unroll
    for (int nt = 0; nt < 4; ++nt)
      bfe[nt] = *(const short8*)&stg[bb][4096 + (wc + nt * 16 + lr) * 32 + sw];
    LGW(); BAR();
    if (k <= 5)      STAGEW(WTe, k + 2, bb);
    else if (k == 6) STAGEW(WTg, 0, 0);
    else             STAGEW(WTg, 1, 1);
    #pragma unroll
    for (int mt = 0; mt < 4; ++mt)
      #pragma unroll
      for (int nt = 0; nt < 4; ++nt)
        accE[mt][nt] = __builtin_amdgcn_mfma_f32_16x16x32_bf16(paf[mt], bfe[nt], accE[mt][nt], 0, 0, 0);
    VMW(2);
    BAR();
  }

  // ---- phase 2b: accG = P @ wg ----
  #pragma unroll
  for (int k = 0; k < 8; ++k) {
    const int bb = k & 1;
    const int kL = (k + ro2) & 7;
    short8 paf[4], bfg[4];
    #pragma unroll
    for (int mt = 0; mt < 4; ++mt)
      paf[mt] = *(const short8*)&pT[xIdx(rb + mt * 16 + lr, 4 * kL + quad)];
    #pragma unroll
    for (int nt = 0; nt < 4; ++nt)
      bfg[nt] = *(const short8*)&stg[bb][4096 + (wc + nt * 16 + lr) * 32 + sw];
    LGW(); BAR();
    if (k <= 5) STAGEW(WTg, k + 2, bb);
    #pragma unroll
    for (int mt = 0; mt < 4; ++mt)
      #pragma unroll
      for (int nt = 0; nt < 4; ++nt)
        accG[mt][nt] = __builtin_amdgcn_mfma_f32_16x16x32_bf16(paf[mt], bfg[nt], accG[mt][nt], 0, 0, 0);
    if (k <= 5)      VMW(2);
    else if (k == 6) VMW(0);           // drain G7 before last round reads it
    if (k <= 6) BAR();
  }

  // ---- epilogue 2: h += (E+be) * sigmoid(G+bg) ----
  float bev[4], bgv[4];
  #pragma unroll
  for (int nt = 0; nt < 4; ++nt) {
    int n = wc + nt * 16 + lr;
    bev[nt] = bev_[n]; bgv[nt] = bgv_[n];
  }
  #pragma unroll
  for (int mt = 0; mt < 4; ++mt)
    #pragma unroll
    for (int r = 0; r < 4; ++r) {
      int row = rb + mt * 16 + quad * 4 + r;
      long off = (long)(m0 + row) * 256;
      #pragma unroll
      for (int nt = 0; nt < 4; ++nt) {
        int n = wc + nt * 16 + lr;
        float e = accE[mt][nt][r] + bev[nt];
        float gg = accG[mt][nt][r] + bgv[nt];
        float hn = e * (1.f / (1.f + expf(-gg))) + b2f(h[off + n]);
        h[off + n] = f2b(hn);
      }
    }
#undef STAGE1
#undef STAGEW
}

// ---------------- final: MFMA logits [M,32], log_softmax, gather next token ----------------

__global__ __launch_bounds__(256) void final_k(const u16* __restrict__ h, const u16* __restrict__ WTo,
                                               const float* __restrict__ outb, const int* __restrict__ x,
                                               float* __restrict__ out) {
  __shared__ u16 lW[32 * 264];
  const int tid = threadIdx.x;
  const int lane = tid & 63;
  const int wv = tid >> 6;
  const int mBase = blockIdx.x * 256 + wv * 64;

  #pragma unroll
  for (int j = 0; j < 4; ++j) {
    int chunk = tid + 256 * j;
    int v = chunk >> 5, k8 = chunk & 31;
    uint4 w4 = *(const uint4*)(WTo + v * 256 + k8 * 8);
    *(uint4*)&lW[v * 264 + k8 * 8] = w4;
  }
  __syncthreads();

  const int lq = (lane >> 4) * 8;
  const int lr = lane & 15;
  const int quad = lane >> 4;

  f32x4 acc[4][2];
  #pragma unroll
  for (int mt = 0; mt < 4; ++mt) {
    acc[mt][0][0] = 0.f; acc[mt][0][1] = 0.f; acc[mt][0][2] = 0.f; acc[mt][0][3] = 0.f;
    acc[mt][1][0] = 0.f; acc[mt][1][1] = 0.f; acc[mt][1][2] = 0.f; acc[mt][1][3] = 0.f;
  }

  for (int kt = 0; kt < 8; ++kt) {
    short8 bf0 = *(const short8*)&lW[lr * 264 + kt * 32 + lq];
    short8 bf1 = *(const short8*)&lW[(16 + lr) * 264 + kt * 32 + lq];
    #pragma unroll
    for (int mt = 0; mt < 4; ++mt) {
      short8 af = *(const short8*)(h + (long)(mBase + mt * 16 + lr) * 256 + kt * 32 + lq);
      acc[mt][0] = __builtin_amdgcn_mfma_f32_16x16x32_bf16(af, bf0, acc[mt][0], 0, 0, 0);
      acc[mt][1] = __builtin_amdgcn_mfma_f32_16x16x32_bf16(af, bf1, acc[mt][1], 0, 0, 0);
    }
  }

  float ob0 = outb[lr], ob1 = outb[16 + lr];
  #pragma unroll
  for (int mt = 0; mt < 4; ++mt)
    #pragma unroll
    for (int r = 0; r < 4; ++r) {
      int row = mBase + mt * 16 + quad * 4 + r;
      float lo = acc[mt][0][r] + ob0;
      float hi = acc[mt][1][r] + ob1;
      float mx = fmaxf(lo, hi);
      #pragma unroll
      for (int o = 1; o < 16; o <<= 1) mx = fmaxf(mx, __shfl_xor(mx, o));
      float se = expf(lo - mx) + expf(hi - mx);
      #pragma unroll
      for (int o = 1; o < 16; o <<= 1) se += __shfl_xor(se, o);
      int s = row & 511;
      int xa = (s == 511) ? row : (row + 1);
      int tok = x[xa];
      float lg = (tok < 16) ? lo : hi;
      float lp = lg - mx - logf(se);
      if (s != 511 && lr == (tok & 15))
        out[(row >> 9) * 511 + s] = lp;
    }
}

// ---------------- launch ----------------

extern "C" void kernel_launch(void* const* d_in, const int* in_sizes, int n_in,
                              void* d_out, int out_size, void* d_ws, size_t ws_size,
                              hipStream_t stream) {
  const int*   x    = (const int*)d_in[0];
  const float* z    = (const float*)d_in[1];
  const float* emb  = (const float*)d_in[2];
  const float* latW = (const float*)d_in[3];
  const float* latb = (const float*)d_in[4];
  const float* ln1g = (const float*)d_in[5];
  const float* ln1b = (const float*)d_in[6];
  const float* w1   = (const float*)d_in[7];
  const float* b1   = (const float*)d_in[8];
  const float* ln2g = (const float*)d_in[9];
  const float* ln2b = (const float*)d_in[10];
  const float* wd   = (const float*)d_in[11];
  const float* bd   = (const float*)d_in[12];
  const float* ln3g = (const float*)d_in[13];
  const float* ln3b = (const float*)d_in[14];
  const float* we   = (const float*)d_in[15];
  const float* be   = (const float*)d_in[16];
  const float* wg   = (const float*)d_in[17];
  const float* bg   = (const float*)d_in[18];
  const float* outW = (const float*)d_in[19];
  const float* outb = (const float*)d_in[20];

  char* ws = (char*)d_ws;
  u16*   h    = (u16*)(ws + 0);               //  67108864  bf16 residual
  u16*   bufA = (u16*)(ws + 67108864);        //  67108864  v
  float* zlat = (float*)(ws + 201326592);     //    262144
  u16*   wT1  = (u16*)(ws + 201588736);       //    917504  [i][n][k]
  u16*   wTd  = (u16*)(ws + 202506240);       //   1835008  [i][n][tap*256+k]
  u16*   wTeg = (u16*)(ws + 204341248);       //   1835008  [i][src][n][k]
  u16*   wTo  = (u16*)(ws + 206176256);       //     16384  [v][k]

  conv_w1_k <<<1792, 256, 0, stream>>>(w1, wT1);
  conv_wd_k <<<3584, 256, 0, stream>>>(wd, wTd);
  conv_weg_k<<<3584, 256, 0, stream>>>(we, wg, wTeg);
  conv_wo_k <<<32, 256, 0, stream>>>(outW, wTo);
  zlat_k    <<<256, 256, 0, stream>>>(z, latW, latb, zlat);
  embed_k   <<<M_DIM / 4, 256, 0, stream>>>(x, emb, zlat, h);

  for (int i = 0; i < NL; ++i) {
    int d = 1 << i;
    // v = lrelu(LN2( lrelu(LN1(h)) @ w1 + b1 ))   -> bufA
    gemm1_k<<<M_DIM / 64, 256, 0, stream>>>(
        h, wT1 + i * 65536, ln1g + i * 256, ln1b + i * 256, b1 + i * 256,
        ln2g + i * 256, ln2b + i * 256, bufA);
    // p = lrelu(LN3(conv)) kept in LDS; h += (p@we+be)*sigmoid(p@wg+bg)
    conv_gate_k<<<M_DIM / 128, 512, 0, stream>>>(
        bufA, wTd + i * 131072, d,
        bd + i * 256, ln3g + i * 256, ln3b + i * 256,
        wTeg + i * 131072, wTeg + i * 131072 + 65536,
        be + i * 256, bg + i * 256, h);
  }

  final_k<<<M_DIM / 256, 256, 0, stream>>>(h, wTo, outb, x, (float*)d_out);
}

// Round 8
// 1387.858 us; speedup vs baseline: 1.0404x; 1.0404x over previous
//
#include <hip/hip_runtime.h>

typedef unsigned short u16;
typedef unsigned int   u32;
typedef __attribute__((ext_vector_type(8))) short short8;
typedef __attribute__((ext_vector_type(4))) float f32x4;

struct __align__(8) u16x4 { u16 x, y, z, w; };

#define NL 7
#define M_DIM 131072              // B*S = 256*512

#define VMW(N) asm volatile("s_waitcnt vmcnt(" #N ")" ::: "memory")
#define LGW()  asm volatile("s_waitcnt lgkmcnt(0)" ::: "memory")
#define BAR()  __builtin_amdgcn_s_barrier()

__device__ __forceinline__ float b2f(u16 u) {
  union { float f; u32 i; } c; c.i = ((u32)u) << 16; return c.f;
}
__device__ __forceinline__ u16 f2b(float f) {
  union { float f; u32 i; } c; c.f = f;
  u32 r = c.i + 0x7FFFu + ((c.i >> 16) & 1u);
  return (u16)(r >> 16);
}
__device__ __forceinline__ void gload16(const void* g, void* l) {
  __builtin_amdgcn_global_load_lds((const __attribute__((address_space(1))) void*)g,
                                   (__attribute__((address_space(3))) void*)l, 16, 0, 0);
}
// XOR-swizzled [R][256] tile index: chunk = col>>3 (8-u16 / 16B units)
__device__ __forceinline__ int xIdx(int row, int chunk) {
  return row * 256 + (((chunk) ^ (row & 7)) << 3);
}

// ---------------- weight conversion (fp32 -> bf16, transposed to [N][K]) ----------------

__global__ __launch_bounds__(256) void conv_w1_k(const float* __restrict__ w1, u16* __restrict__ wT) {
  int idx = blockIdx.x * 256 + threadIdx.x;            // NL*256*256 ; [i][n][k]
  int i = idx >> 16, rem = idx & 65535;
  int n = rem >> 8, k = rem & 255;
  wT[idx] = f2b(w1[(i << 16) + (k << 8) + n]);
}

__global__ __launch_bounds__(256) void conv_wd_k(const float* __restrict__ wd, u16* __restrict__ wT) {
  int idx = blockIdx.x * 256 + threadIdx.x;            // NL*256*512 ; [i][n][k2], k2=tap*256+k
  int i = idx / 131072, rem = idx & 131071;
  int n = rem >> 9, k2 = rem & 511;
  int tap = k2 >> 8, k = k2 & 255;
  wT[idx] = f2b(wd[(((i * 2 + tap) << 8) + k) * 256 + n]);
}

__global__ __launch_bounds__(256) void conv_weg_k(const float* __restrict__ we, const float* __restrict__ wg,
                                                  u16* __restrict__ wT) {
  int idx = blockIdx.x * 256 + threadIdx.x;            // NL*2*256*256 ; [i][src][n][k]
  int i = idx / 131072, rem = idx & 131071;
  int src = rem >> 16, n = (rem >> 8) & 255, k = rem & 255;
  const float* W = src ? wg : we;
  wT[idx] = f2b(W[((i << 8) + k) * 256 + n]);
}

__global__ __launch_bounds__(256) void conv_wo_k(const float* __restrict__ outW, u16* __restrict__ wTo) {
  int idx = blockIdx.x * 256 + threadIdx.x;            // 32*256 ; [v][k]
  int v = idx >> 8, k = idx & 255;
  wTo[idx] = f2b(outW[k * 32 + v]);
}

// ---------------- zlat = z @ latent_W + latent_b  [256,256] fp32 ----------------

__global__ __launch_bounds__(256) void zlat_k(const float* __restrict__ z, const float* __restrict__ W,
                                              const float* __restrict__ bias, float* __restrict__ zlat) {
  int b = blockIdx.x, c = threadIdx.x;
  float acc = bias[c];
  for (int l = 0; l < 256; ++l) acc += z[b * 256 + l] * W[l * 256 + c];
  zlat[b * 256 + c] = acc;
}

// ---------------- embed: h = bf16(emb[x] + zlat) ----------------

__global__ __launch_bounds__(256) void embed_k(const int* __restrict__ x, const float* __restrict__ emb,
                                               const float* __restrict__ zlat, u16* __restrict__ h) {
  int wave = threadIdx.x >> 6, lane = threadIdx.x & 63;
  int r = blockIdx.x * 4 + wave;
  int c = lane * 4;
  int tok = x[r];
  int bi = r >> 9;
  float4 ev = *(const float4*)&emb[tok * 256 + c];
  float4 zv = *(const float4*)&zlat[bi * 256 + c];
  u16x4 hb;
  hb.x = f2b(ev.x + zv.x); hb.y = f2b(ev.y + zv.y);
  hb.z = f2b(ev.z + zv.z); hb.w = f2b(ev.w + zv.w);
  *(u16x4*)&h[(long)r * 256 + c] = hb;
}

// ---------------- gemm1: V = lrelu(LN2( lrelu(LN1(h)) @ w1 + b1 )) ----------------
// r4 proven shape (no rotation): 48KB LDS -> 3 blocks/CU.

__global__ __launch_bounds__(256, 3) void gemm1_k(
    const u16* __restrict__ h, const u16* __restrict__ WT,
    const float* __restrict__ ln1g, const float* __restrict__ ln1b,
    const float* __restrict__ bias,
    const float* __restrict__ ln2g, const float* __restrict__ ln2b,
    u16* __restrict__ V)
{
  __shared__ __align__(16) u16 lA[64 * 256];     // 32768 B, LN1(h) tile, XOR-swizzled
  __shared__ __align__(16) u16 lB[256 * 32];     // 16384 B, per-kt B staging
  float* pS  = (float*)lB;
  float* pQ  = (float*)(lB + 512);
  float* muA = (float*)(lB + 1024);
  float* rsA = (float*)(lB + 1152);
  const int tid = threadIdx.x;
  const int lane = tid & 63;
  const int wv = tid >> 6;            // 0..3
  const int wc = wv * 64;
  const int m0 = blockIdx.x * 64;
  const int rA = tid >> 2;            // 0..63
  const int cSw = ((((tid & 3) - ((tid >> 3) & 3)) & 3)) * 8;
  const int lr = lane & 15;
  const int quad = lane >> 4;
  const int sw = ((quad + ((lr >> 1) & 3)) & 3) * 8;

  // ---- prologue: LN1 + lrelu of 16 rows per wave -> lA ----
  {
    const int half = lane >> 5, l5 = lane & 31;
    float4 ga = *(const float4*)&ln1g[l5 * 8];
    float4 gb = *(const float4*)&ln1g[l5 * 8 + 4];
    float4 ba = *(const float4*)&ln1b[l5 * 8];
    float4 bb = *(const float4*)&ln1b[l5 * 8 + 4];
    #pragma unroll 4
    for (int it = 0; it < 8; ++it) {
      int row = wv * 16 + it * 2 + half;
      uint4 hv = *(const uint4*)(h + (long)(m0 + row) * 256 + l5 * 8);
      float v0 = b2f((u16)(hv.x & 0xffff)), v1 = b2f((u16)(hv.x >> 16));
      float v2 = b2f((u16)(hv.y & 0xffff)), v3 = b2f((u16)(hv.y >> 16));
      float v4 = b2f((u16)(hv.z & 0xffff)), v5 = b2f((u16)(hv.z >> 16));
      float v6 = b2f((u16)(hv.w & 0xffff)), v7 = b2f((u16)(hv.w >> 16));
      float s = v0 + v1 + v2 + v3 + v4 + v5 + v6 + v7;
      float q = v0*v0 + v1*v1 + v2*v2 + v3*v3 + v4*v4 + v5*v5 + v6*v6 + v7*v7;
      #pragma unroll
      for (int o = 1; o < 32; o <<= 1) { s += __shfl_xor(s, o); q += __shfl_xor(q, o); }
      float mu = s * 0.00390625f;
      float var = q * 0.00390625f - mu * mu;
      float rs = rsqrtf(var + 1e-5f);
      float y0 = (v0 - mu) * rs * ga.x + ba.x; y0 = y0 >= 0.f ? y0 : 0.01f * y0;
      float y1 = (v1 - mu) * rs * ga.y + ba.y; y1 = y1 >= 0.f ? y1 : 0.01f * y1;
      float y2 = (v2 - mu) * rs * ga.z + ba.z; y2 = y2 >= 0.f ? y2 : 0.01f * y2;
      float y3 = (v3 - mu) * rs * ga.w + ba.w; y3 = y3 >= 0.f ? y3 : 0.01f * y3;
      float y4 = (v4 - mu) * rs * gb.x + bb.x; y4 = y4 >= 0.f ? y4 : 0.01f * y4;
      float y5 = (v5 - mu) * rs * gb.y + bb.y; y5 = y5 >= 0.f ? y5 : 0.01f * y5;
      float y6 = (v6 - mu) * rs * gb.z + bb.z; y6 = y6 >= 0.f ? y6 : 0.01f * y6;
      float y7 = (v7 - mu) * rs * gb.w + bb.w; y7 = y7 >= 0.f ? y7 : 0.01f * y7;
      uint4 ov;
      ov.x = (u32)f2b(y0) | ((u32)f2b(y1) << 16);
      ov.y = (u32)f2b(y2) | ((u32)f2b(y3) << 16);
      ov.z = (u32)f2b(y4) | ((u32)f2b(y5) << 16);
      ov.w = (u32)f2b(y6) | ((u32)f2b(y7) << 16);
      *(uint4*)&lA[xIdx(row, l5)] = ov;
    }
  }

  f32x4 acc[4][4];
  #pragma unroll
  for (int i = 0; i < 4; ++i)
    #pragma unroll
    for (int j = 0; j < 4; ++j) {
      acc[i][j][0] = 0.f; acc[i][j][1] = 0.f; acc[i][j][2] = 0.f; acc[i][j][3] = 0.f;
    }

  for (int kt = 0; kt < 8; ++kt) {
    const long bofs = (long)rA * 256 + kt * 32 + cSw;
    #pragma unroll
    for (int j = 0; j < 4; ++j)
      gload16(WT + bofs + (long)(64 * j) * 256, &lB[tid * 8 + j * 2048]);
    __syncthreads();

    short8 af[4], bfr[4];
    #pragma unroll
    for (int mt = 0; mt < 4; ++mt)
      af[mt] = *(const short8*)&lA[xIdx(mt * 16 + lr, 4 * kt + quad)];
    #pragma unroll
    for (int nt = 0; nt < 4; ++nt)
      bfr[nt] = *(const short8*)&lB[(wc + nt * 16 + lr) * 32 + sw];
    #pragma unroll
    for (int mt = 0; mt < 4; ++mt)
      #pragma unroll
      for (int nt = 0; nt < 4; ++nt)
        acc[mt][nt] = __builtin_amdgcn_mfma_f32_16x16x32_bf16(af[mt], bfr[nt], acc[mt][nt], 0, 0, 0);
    __syncthreads();
  }

  // ---- epilogue: bias + LN2 + lrelu -> V ----
  float biasv[4], gv[4], bv[4];
  #pragma unroll
  for (int nt = 0; nt < 4; ++nt) {
    int n = wc + nt * 16 + lr;
    biasv[nt] = bias[n]; gv[nt] = ln2g[n]; bv[nt] = ln2b[n];
  }
  #pragma unroll
  for (int mt = 0; mt < 4; ++mt)
    #pragma unroll
    for (int r = 0; r < 4; ++r) {
      float s = 0.f, q = 0.f;
      #pragma unroll
      for (int nt = 0; nt < 4; ++nt) {
        float v = acc[mt][nt][r] + biasv[nt];
        acc[mt][nt][r] = v;
        s += v; q += v * v;
      }
      #pragma unroll
      for (int o = 1; o < 16; o <<= 1) { s += __shfl_xor(s, o); q += __shfl_xor(q, o); }
      if (lr == 0) { pS[(mt * 16 + quad * 4 + r) * 4 + wv] = s; pQ[(mt * 16 + quad * 4 + r) * 4 + wv] = q; }
    }
  __syncthreads();
  if (tid < 64) {
    float S = pS[tid * 4 + 0] + pS[tid * 4 + 1] + pS[tid * 4 + 2] + pS[tid * 4 + 3];
    float Q = pQ[tid * 4 + 0] + pQ[tid * 4 + 1] + pQ[tid * 4 + 2] + pQ[tid * 4 + 3];
    float mu = S * 0.00390625f;
    float var = Q * 0.00390625f - mu * mu;
    muA[tid] = mu; rsA[tid] = rsqrtf(var + 1e-5f);
  }
  __syncthreads();
  #pragma unroll
  for (int mt = 0; mt < 4; ++mt)
    #pragma unroll
    for (int r = 0; r < 4; ++r) {
      int row = mt * 16 + quad * 4 + r;
      float mu = muA[row], rs = rsA[row];
      #pragma unroll
      for (int nt = 0; nt < 4; ++nt) {
        float y = (acc[mt][nt][r] - mu) * rs * gv[nt] + bv[nt];
        y = y >= 0.f ? y : 0.01f * y;
        V[(long)(m0 + row) * 256 + wc + nt * 16 + lr] = f2b(y);
      }
    }
}

// ---------------- FUSED conv+LN3+lrelu -> P(LDS) -> gate GEMMs -> h update ----------------
// r8 = r7 with the LDS stride bug fixed: stgW per-buffer stride is 16384 u16
// (32KB), NOT 32768 (that was a bytes-as-u16 error -> OOB for bb=1).
// BK=64 -> 16 rounds total (8 conv + 4 E + 4 G), 2x MFMA payload per round to
// amortize per-round fixed costs. LDS 144KB: pT 64KB + A 16KB + W dbuf 2x32KB.

__global__ __launch_bounds__(512, 2) void conv_gate_k(
    const u16* __restrict__ A,      // v  [M][256] bf16
    const u16* __restrict__ WTd,    // [256][512]  (n-major; k2 = tap*256+k)
    int dil,
    const float* __restrict__ bd3, const float* __restrict__ g3, const float* __restrict__ bb3,
    const u16* __restrict__ WTe, const u16* __restrict__ WTg,   // [256][256] each
    const float* __restrict__ bev_, const float* __restrict__ bgv_,
    u16* __restrict__ h)
{
  __shared__ __align__(16) u16 lds[73728];       // 147456 B total
  u16* pT   = lds;                // [128][256] XOR-swizzled, 65536 B
  u16* stgA = lds + 32768;        // [2 sub][128][32] = 16384 B (single-buffered)
  u16* stgW = lds + 40960;        // [2 buf][2 sub][256][32] = 65536 B (double-buffered)
  // stats aliased into stgA (A region dead after phase 1)
  float* pS  = (float*)stgA;            // [128][4]  bytes [0,2048)
  float* pQ  = (float*)(stgA + 1024);   //           bytes [2048,4096)
  float* muA = (float*)(stgA + 2048);   //           bytes [4096,4608)
  float* rsA = (float*)(stgA + 2304);   //           bytes [4608,5120)

  const int tid = threadIdx.x;
  const int lane = tid & 63;
  const int wv = tid >> 6;            // 0..7
  const int mw = wv >> 2;             // 0..1
  const int nw = wv & 3;              // 0..3
  const int rb = mw * 64;
  const int wc = nw * 64;
  const int m0 = blockIdx.x * 128;
  const int rA = tid >> 2;            // 0..127
  const int cSw = ((((tid & 3) - ((tid >> 3) & 3)) & 3)) * 8;
  const int lr = lane & 15;
  const int quad = lane >> 4;
  const int sw = ((quad + ((lr >> 1) & 3)) & 3) * 8;
  const int mm = m0 + rA;
  const int s1 = mm & 511;
  const short8 zero8 = {0, 0, 0, 0, 0, 0, 0, 0};

  // tap0 zero predicate per frag row
  bool zz[4];
  #pragma unroll
  for (int mt = 0; mt < 4; ++mt)
    zz[mt] = ((m0 + rb + mt * 16 + lr) & 511) < dil;

  // thread-baked base pointers (all per-round addresses = base + literal offset)
  const int rowA0 = (s1 >= dil) ? (mm - dil) : mm;         // tap0 source row (junk rows frag-zeroed)
  const u16* pA0 = A + (long)rowA0 * 256 + cSw;            // rounds 0-3, advance (r&3)*64
  const u16* pA1 = A + (long)mm * 256 + cSw;               // rounds 4-7
  const u16* pWd = WTd + (long)rA * 512 + cSw;             // rows rA, rA+128 (+65536)
  const u16* pWe = WTe + (long)rA * 256 + cSw;             // rows rA, rA+128 (+32768)
  const u16* pWg = WTg + (long)rA * 256 + cSw;

  // A staging: 2 loads/thread, round kt covers cols [ (kt&3)*64, +64 )
  auto STAGE_A = [&](int kt) {
    const u16* pa = (kt < 4 ? pA0 : pA1) + (kt & 3) * 64;
    gload16(pa,      &stgA[tid * 8]);
    gload16(pa + 32, &stgA[4096 + tid * 8]);
  };
  // phase-1 W staging: 4 loads/thread, round kt covers WTd cols [kt*64, +64)
  auto STAGE_W1 = [&](int kt, int bb) {
    const u16* pw = pWd + kt * 64;
    u16* d = &stgW[bb * 16384];
    gload16(pw,              &d[tid * 8]);
    gload16(pw + 65536,      &d[tid * 8 + 4096]);
    gload16(pw + 32,         &d[8192 + tid * 8]);
    gload16(pw + 65536 + 32, &d[8192 + tid * 8 + 4096]);
  };
  // phase-2 W staging: 4 loads/thread, cols [kt*64, +64) of a [256][256] matrix
  auto STAGE_W2 = [&](const u16* base, int kt, int bb) {
    const u16* pw = base + kt * 64;
    u16* d = &stgW[bb * 16384];
    gload16(pw,              &d[tid * 8]);
    gload16(pw + 32768,      &d[tid * 8 + 4096]);
    gload16(pw + 32,         &d[8192 + tid * 8]);
    gload16(pw + 32768 + 32, &d[8192 + tid * 8 + 4096]);
  };

  f32x4 acc[4][4];
  #pragma unroll
  for (int i = 0; i < 4; ++i)
    #pragma unroll
    for (int j = 0; j < 4; ++j) {
      acc[i][j][0] = 0.f; acc[i][j][1] = 0.f; acc[i][j][2] = 0.f; acc[i][j][3] = 0.f;
    }

  // ---- phase 1: conv GEMM, Ktot=512, BK=64 -> 8 rounds (0-3 tap0, 4-7 tap1) ----
  STAGE_A(0);
  STAGE_W1(0, 0);
  STAGE_W1(1, 1);
  VMW(4);                              // A0+W0 staged (W1's 4 still in flight)
  BAR();

  #pragma unroll
  for (int r = 0; r < 8; ++r) {
    const int bb = r & 1;
    short8 af[2][4], bfr[2][4];
    #pragma unroll
    for (int s = 0; s < 2; ++s)
      #pragma unroll
      for (int mt = 0; mt < 4; ++mt) {
        af[s][mt] = *(const short8*)&stgA[s * 4096 + (rb + mt * 16 + lr) * 32 + sw];
        if (r < 4 && zz[mt]) af[s][mt] = zero8;
      }
    #pragma unroll
    for (int s = 0; s < 2; ++s)
      #pragma unroll
      for (int nt = 0; nt < 4; ++nt)
        bfr[s][nt] = *(const short8*)&stgW[bb * 16384 + s * 8192 + (wc + nt * 16 + lr) * 32 + sw];
    LGW();                             // frags in regs
    BAR();                             // all waves done reading stgA + stgW[bb]
    if (r <= 5)      { STAGE_A(r + 1); STAGE_W1(r + 2, bb); }
    else if (r == 6) { STAGE_A(7);     STAGE_W2(pWe, 0, 0); }   // prefetch E0
    else             {                 STAGE_W2(pWe, 1, 1); }   // r==7: E1
    #pragma unroll
    for (int s = 0; s < 2; ++s)
      #pragma unroll
      for (int mt = 0; mt < 4; ++mt)
        #pragma unroll
        for (int nt = 0; nt < 4; ++nt)
          acc[mt][nt] = __builtin_amdgcn_mfma_f32_16x16x32_bf16(af[s][mt], bfr[s][nt], acc[mt][nt], 0, 0, 0);
    if (r <= 6) VMW(4);                // next round's A+W complete (newest 4 keep flying)
    BAR();
  }

  // ---- epilogue 1: bias + LN3 stats + lrelu -> pT (stats in stgA region) ----
  float b3v[4], g3v[4], o3v[4];
  #pragma unroll
  for (int nt = 0; nt < 4; ++nt) {
    int n = wc + nt * 16 + lr;
    b3v[nt] = bd3[n]; g3v[nt] = g3[n]; o3v[nt] = bb3[n];
  }
  #pragma unroll
  for (int mt = 0; mt < 4; ++mt)
    #pragma unroll
    for (int r = 0; r < 4; ++r) {
      float s = 0.f, q = 0.f;
      #pragma unroll
      for (int nt = 0; nt < 4; ++nt) {
        float v = acc[mt][nt][r] + b3v[nt];
        acc[mt][nt][r] = v;
        s += v; q += v * v;
      }
      #pragma unroll
      for (int o = 1; o < 16; o <<= 1) { s += __shfl_xor(s, o); q += __shfl_xor(q, o); }
      if (lr == 0) {
        int row = rb + mt * 16 + quad * 4 + r;
        pS[row * 4 + nw] = s; pQ[row * 4 + nw] = q;
      }
    }
  LGW(); BAR();
  if (tid < 128) {
    float S = pS[tid * 4 + 0] + pS[tid * 4 + 1] + pS[tid * 4 + 2] + pS[tid * 4 + 3];
    float Q = pQ[tid * 4 + 0] + pQ[tid * 4 + 1] + pQ[tid * 4 + 2] + pQ[tid * 4 + 3];
    float mu = S * 0.00390625f;
    float var = Q * 0.00390625f - mu * mu;
    muA[tid] = mu; rsA[tid] = rsqrtf(var + 1e-5f);
  }
  LGW(); BAR();
  #pragma unroll
  for (int mt = 0; mt < 4; ++mt)
    #pragma unroll
    for (int r = 0; r < 4; ++r) {
      int row = rb + mt * 16 + quad * 4 + r;
      float mu = muA[row], rs = rsA[row];
      #pragma unroll
      for (int nt = 0; nt < 4; ++nt) {
        int col = wc + nt * 16 + lr;
        float y = (acc[mt][nt][r] - mu) * rs * g3v[nt] + o3v[nt];
        y = y >= 0.f ? y : 0.01f * y;
        pT[xIdx(row, col >> 3) + (col & 7)] = f2b(y);
      }
    }
  LGW(); VMW(4); BAR();                // pT visible; E0 staged (E1 in flight)

  // ---- phase 2a: accE = P @ we (K=256, BK=64 -> 4 rounds, W dbuf counted) ----
  f32x4 accE[4][4], accG[4][4];
  #pragma unroll
  for (int i = 0; i < 4; ++i)
    #pragma unroll
    for (int j = 0; j < 4; ++j) {
      accE[i][j][0] = 0.f; accE[i][j][1] = 0.f; accE[i][j][2] = 0.f; accE[i][j][3] = 0.f;
      accG[i][j][0] = 0.f; accG[i][j][1] = 0.f; accG[i][j][2] = 0.f; accG[i][j][3] = 0.f;
    }

  #pragma unroll
  for (int k = 0; k < 4; ++k) {
    const int bb = k & 1;
    short8 paf[2][4], bfe[2][4];
    #pragma unroll
    for (int s = 0; s < 2; ++s)
      #pragma unroll
      for (int mt = 0; mt < 4; ++mt)
        paf[s][mt] = *(const short8*)&pT[xIdx(rb + mt * 16 + lr, k * 8 + s * 4 + quad)];
    #pragma unroll
    for (int s = 0; s < 2; ++s)
      #pragma unroll
      for (int nt = 0; nt < 4; ++nt)
        bfe[s][nt] = *(const short8*)&stgW[bb * 16384 + s * 8192 + (wc + nt * 16 + lr) * 32 + sw];
    LGW(); BAR();
    if (k == 0)      STAGE_W2(pWe, 2, 0);
    else if (k == 1) STAGE_W2(pWe, 3, 1);
    else if (k == 2) STAGE_W2(pWg, 0, 0);
    else             STAGE_W2(pWg, 1, 1);
    #pragma unroll
    for (int s = 0; s < 2; ++s)
      #pragma unroll
      for (int mt = 0; mt < 4; ++mt)
        #pragma unroll
        for (int nt = 0; nt < 4; ++nt)
          accE[mt][nt] = __builtin_amdgcn_mfma_f32_16x16x32_bf16(paf[s][mt], bfe[s][nt], accE[mt][nt], 0, 0, 0);
    VMW(4);
    BAR();
  }

  // ---- phase 2b: accG = P @ wg (4 rounds) ----
  #pragma unroll
  for (int k = 0; k < 4; ++k) {
    const int bb = k & 1;
    short8 paf[2][4], bfg[2][4];
    #pragma unroll
    for (int s = 0; s < 2; ++s)
      #pragma unroll
      for (int mt = 0; mt < 4; ++mt)
        paf[s][mt] = *(const short8*)&pT[xIdx(rb + mt * 16 + lr, k * 8 + s * 4 + quad)];
    #pragma unroll
    for (int s = 0; s < 2; ++s)
      #pragma unroll
      for (int nt = 0; nt < 4; ++nt)
        bfg[s][nt] = *(const short8*)&stgW[bb * 16384 + s * 8192 + (wc + nt * 16 + lr) * 32 + sw];
    LGW(); BAR();
    if (k == 0)      STAGE_W2(pWg, 2, 0);
    else if (k == 1) STAGE_W2(pWg, 3, 1);
    #pragma unroll
    for (int s = 0; s < 2; ++s)
      #pragma unroll
      for (int mt = 0; mt < 4; ++mt)
        #pragma unroll
        for (int nt = 0; nt < 4; ++nt)
          accG[mt][nt] = __builtin_amdgcn_mfma_f32_16x16x32_bf16(paf[s][mt], bfg[s][nt], accG[mt][nt], 0, 0, 0);
    if (k <= 1)      VMW(4);
    else if (k == 2) VMW(0);           // drain G3 before last round reads it
    if (k <= 2) BAR();
  }

  // ---- epilogue 2: h += (E+be) * sigmoid(G+bg) ----
  float bev[4], bgv[4];
  #pragma unroll
  for (int nt = 0; nt < 4; ++nt) {
    int n = wc + nt * 16 + lr;
    bev[nt] = bev_[n]; bgv[nt] = bgv_[n];
  }
  #pragma unroll
  for (int mt = 0; mt < 4; ++mt)
    #pragma unroll
    for (int r = 0; r < 4; ++r) {
      int row = rb + mt * 16 + quad * 4 + r;
      long off = (long)(m0 + row) * 256;
      #pragma unroll
      for (int nt = 0; nt < 4; ++nt) {
        int n = wc + nt * 16 + lr;
        float e = accE[mt][nt][r] + bev[nt];
        float gg = accG[mt][nt][r] + bgv[nt];
        float hn = e * (1.f / (1.f + expf(-gg))) + b2f(h[off + n]);
        h[off + n] = f2b(hn);
      }
    }
}

// ---------------- final: MFMA logits [M,32], log_softmax, gather next token ----------------

__global__ __launch_bounds__(256) void final_k(const u16* __restrict__ h, const u16* __restrict__ WTo,
                                               const float* __restrict__ outb, const int* __restrict__ x,
                                               float* __restrict__ out) {
  __shared__ u16 lW[32 * 264];
  const int tid = threadIdx.x;
  const int lane = tid & 63;
  const int wv = tid >> 6;
  const int mBase = blockIdx.x * 256 + wv * 64;

  #pragma unroll
  for (int j = 0; j < 4; ++j) {
    int chunk = tid + 256 * j;
    int v = chunk >> 5, k8 = chunk & 31;
    uint4 w4 = *(const uint4*)(WTo + v * 256 + k8 * 8);
    *(uint4*)&lW[v * 264 + k8 * 8] = w4;
  }
  __syncthreads();

  const int lq = (lane >> 4) * 8;
  const int lr = lane & 15;
  const int quad = lane >> 4;

  f32x4 acc[4][2];
  #pragma unroll
  for (int mt = 0; mt < 4; ++mt) {
    acc[mt][0][0] = 0.f; acc[mt][0][1] = 0.f; acc[mt][0][2] = 0.f; acc[mt][0][3] = 0.f;
    acc[mt][1][0] = 0.f; acc[mt][1][1] = 0.f; acc[mt][1][2] = 0.f; acc[mt][1][3] = 0.f;
  }

  for (int kt = 0; kt < 8; ++kt) {
    short8 bf0 = *(const short8*)&lW[lr * 264 + kt * 32 + lq];
    short8 bf1 = *(const short8*)&lW[(16 + lr) * 264 + kt * 32 + lq];
    #pragma unroll
    for (int mt = 0; mt < 4; ++mt) {
      short8 af = *(const short8*)(h + (long)(mBase + mt * 16 + lr) * 256 + kt * 32 + lq);
      acc[mt][0] = __builtin_amdgcn_mfma_f32_16x16x32_bf16(af, bf0, acc[mt][0], 0, 0, 0);
      acc[mt][1] = __builtin_amdgcn_mfma_f32_16x16x32_bf16(af, bf1, acc[mt][1], 0, 0, 0);
    }
  }

  float ob0 = outb[lr], ob1 = outb[16 + lr];
  #pragma unroll
  for (int mt = 0; mt < 4; ++mt)
    #pragma unroll
    for (int r = 0; r < 4; ++r) {
      int row = mBase + mt * 16 + quad * 4 + r;
      float lo = acc[mt][0][r] + ob0;
      float hi = acc[mt][1][r] + ob1;
      float mx = fmaxf(lo, hi);
      #pragma unroll
      for (int o = 1; o < 16; o <<= 1) mx = fmaxf(mx, __shfl_xor(mx, o));
      float se = expf(lo - mx) + expf(hi - mx);
      #pragma unroll
      for (int o = 1; o < 16; o <<= 1) se += __shfl_xor(se, o);
      int s = row & 511;
      int xa = (s == 511) ? row : (row + 1);
      int tok = x[xa];
      float lg = (tok < 16) ? lo : hi;
      float lp = lg - mx - logf(se);
      if (s != 511 && lr == (tok & 15))
        out[(row >> 9) * 511 + s] = lp;
    }
}

// ---------------- launch ----------------

extern "C" void kernel_launch(void* const* d_in, const int* in_sizes, int n_in,
                              void* d_out, int out_size, void* d_ws, size_t ws_size,
                              hipStream_t stream) {
  const int*   x    = (const int*)d_in[0];
  const float* z    = (const float*)d_in[1];
  const float* emb  = (const float*)d_in[2];
  const float* latW = (const float*)d_in[3];
  const float* latb = (const float*)d_in[4];
  const float* ln1g = (const float*)d_in[5];
  const float* ln1b = (const float*)d_in[6];
  const float* w1   = (const float*)d_in[7];
  const float* b1   = (const float*)d_in[8];
  const float* ln2g = (const float*)d_in[9];
  const float* ln2b = (const float*)d_in[10];
  const float* wd   = (const float*)d_in[11];
  const float* bd   = (const float*)d_in[12];
  const float* ln3g = (const float*)d_in[13];
  const float* ln3b = (const float*)d_in[14];
  const float* we   = (const float*)d_in[15];
  const float* be   = (const float*)d_in[16];
  const float* wg   = (const float*)d_in[17];
  const float* bg   = (const float*)d_in[18];
  const float* outW = (const float*)d_in[19];
  const float* outb = (const float*)d_in[20];

  char* ws = (char*)d_ws;
  u16*   h    = (u16*)(ws + 0);               //  67108864  bf16 residual
  u16*   bufA = (u16*)(ws + 67108864);        //  67108864  v
  float* zlat = (float*)(ws + 201326592);     //    262144
  u16*   wT1  = (u16*)(ws + 201588736);       //    917504  [i][n][k]
  u16*   wTd  = (u16*)(ws + 202506240);       //   1835008  [i][n][tap*256+k]
  u16*   wTeg = (u16*)(ws + 204341248);       //   1835008  [i][src][n][k]
  u16*   wTo  = (u16*)(ws + 206176256);       //     16384  [v][k]

  conv_w1_k <<<1792, 256, 0, stream>>>(w1, wT1);
  conv_wd_k <<<3584, 256, 0, stream>>>(wd, wTd);
  conv_weg_k<<<3584, 256, 0, stream>>>(we, wg, wTeg);
  conv_wo_k <<<32, 256, 0, stream>>>(outW, wTo);
  zlat_k    <<<256, 256, 0, stream>>>(z, latW, latb, zlat);
  embed_k   <<<M_DIM / 4, 256, 0, stream>>>(x, emb, zlat, h);

  for (int i = 0; i < NL; ++i) {
    int d = 1 << i;
    // v = lrelu(LN2( lrelu(LN1(h)) @ w1 + b1 ))   -> bufA
    gemm1_k<<<M_DIM / 64, 256, 0, stream>>>(
        h, wT1 + i * 65536, ln1g + i * 256, ln1b + i * 256, b1 + i * 256,
        ln2g + i * 256, ln2b + i * 256, bufA);
    // p = lrelu(LN3(conv)) kept in LDS; h += (p@we+be)*sigmoid(p@wg+bg)
    conv_gate_k<<<M_DIM / 128, 512, 0, stream>>>(
        bufA, wTd + i * 131072, d,
        bd + i * 256, ln3g + i * 256, ln3b + i * 256,
        wTeg + i * 131072, wTeg + i * 131072 + 65536,
        be + i * 256, bg + i * 256, h);
  }

  final_k<<<M_DIM / 256, 256, 0, stream>>>(h, wTo, outb, x, (float*)d_out);
}